// Round 1
// baseline (255.597 us; speedup 1.0000x reference)
//
#include <hip/hip_runtime.h>
#include <float.h>
#include <math.h>

#define NJ   24
#define COL  14
#define CC   196        // COL*COL
#define CC3  2744       // COL^3
#define NV4_3D 686      // CC3/4
#define NV4_2D 49       // CC/4
#define TMPW 3

// acc layout (doubles): [0]=S1 [1]=S2 [2]=S3 [3]=S4 [4]=CNT [5]=NVSUM
__global__ __launch_bounds__(256)
void msed_pair_kernel(const float* __restrict__ o,
                      const float* __restrict__ h,
                      const float* __restrict__ o3D,
                      const float* __restrict__ h3D,
                      const float* __restrict__ t,
                      const float* __restrict__ t3D,
                      const float* __restrict__ v,
                      double* __restrict__ acc)
{
    const int pair = blockIdx.x;     // b*NJ + j
    const int tid  = threadIdx.x;

    __shared__ int sh[9];            // active, jm, gate2, gate3, mux, muy, m3x, m3y, m3z
    __shared__ float rs1[4], rs3[4], rv2[4], rv3[4];
    __shared__ int   ri2[4], ri3[4];

    // thread 0 keeps these in registers for the epilogue
    float tx = 0.f, ty = 0.f, t3x = 0.f, t3y = 0.f, t3z = 0.f;
    float vf0 = 0.f, vf1 = 0.f, vf2 = 0.f;
    bool vis = false, valid2d = false;

    if (tid == 0) {
        tx  = t[pair * 2 + 0];  ty  = t[pair * 2 + 1];
        t3x = t3D[pair * 3 + 0]; t3y = t3D[pair * 3 + 1]; t3z = t3D[pair * 3 + 2];
        float v0 = v[pair * 3 + 0], v1 = v[pair * 3 + 1], v2c = v[pair * 3 + 2];
        vis = (v0 == 1.0f);

        int mux = (int)floorf(tx * (float)COL + 0.5f);
        int muy = (int)floorf(ty * (float)COL + 0.5f);
        valid2d = !((mux - TMPW >= COL) || (muy - TMPW >= COL) ||
                    (mux + TMPW + 1 <= 0) || (muy + TMPW + 1 <= 0));

        int m3x = (int)floorf(t3x * (float)COL + 0.5f);
        int m3y = (int)floorf(t3y * (float)COL + 0.5f);
        int m3z = (int)floorf(t3z * (float)COL + 7.0f + 0.5f);
        bool valid3d = !((m3x - TMPW >= COL) || (m3y - TMPW >= COL) || (m3z - TMPW >= COL) ||
                         (m3x + TMPW + 1 < 0) || (m3y + TMPW + 1 < 0) || (m3z + TMPW + 1 < 0));

        float keep = vis ? ((valid2d && valid3d) ? 1.0f : 0.0f) : 1.0f;
        vf0 = v0 * keep; vf1 = v1 * keep; vf2 = v2c * keep;
        bool jm = (vf0 != 0.0f);
        bool active = jm || (vf1 != 0.0f) || (vf2 != 0.0f);

        sh[0] = active ? 1 : 0;
        sh[1] = jm ? 1 : 0;
        sh[2] = (vis && valid2d) ? 1 : 0;
        sh[3] = (vis && valid2d && valid3d) ? 1 : 0;
        sh[4] = mux; sh[5] = muy; sh[6] = m3x; sh[7] = m3y; sh[8] = m3z;
    }
    __syncthreads();

    if (!sh[0]) return;              // pair contributes nothing at all
    const bool jm    = sh[1] != 0;
    const bool gate2 = sh[2] != 0;
    const bool gate3 = sh[3] != 0;
    const int mux = sh[4], muy = sh[5], m3x = sh[6], m3y = sh[7], m3z = sh[8];

    // ---------- fused 3D pass: argmax + sum (h3 - tt3)^2 ----------
    const float4* hp3 = (const float4*)(h3D + (size_t)pair * CC3);
    float s3 = 0.0f;
    float bv3 = -FLT_MAX; int bi3 = 0x7FFFFFFF;
    for (int i = tid; i < NV4_3D; i += 256) {
        float4 q = hp3[i];
        float vals[4] = {q.x, q.y, q.z, q.w};
        int e0 = i * 4;
        #pragma unroll
        for (int c = 0; c < 4; ++c) {
            int e = e0 + c;
            float hv = vals[c];
            if (hv > bv3) { bv3 = hv; bi3 = e; }   // increasing e per-thread -> first max kept
            int z = e / CC; int r = e - z * CC; int y = r / COL; int x = r - y * COL;
            float g = 0.0f;
            int dx = x - m3x, dy = y - m3y, dz = z - m3z;
            if (gate3 && abs(dx) <= TMPW && abs(dy) <= TMPW && abs(dz) <= TMPW) {
                g = expf(-0.5f * (float)(dx * dx + dy * dy + dz * dz));
            }
            float df = hv - g;
            s3 += df * df;
        }
    }

    // ---------- fused 2D pass ----------
    float s1 = 0.0f;
    float bv2 = -FLT_MAX; int bi2 = 0x7FFFFFFF;
    if (tid < NV4_2D) {
        const float4* hp2 = (const float4*)(h + (size_t)pair * CC);
        float4 q = hp2[tid];
        float vals[4] = {q.x, q.y, q.z, q.w};
        int e0 = tid * 4;
        #pragma unroll
        for (int c = 0; c < 4; ++c) {
            int e = e0 + c;
            float hv = vals[c];
            if (hv > bv2) { bv2 = hv; bi2 = e; }
            int y = e / COL; int x = e - y * COL;
            float g = 0.0f;
            int dx = x - mux, dy = y - muy;
            if (gate2 && abs(dx) <= TMPW && abs(dy) <= TMPW) {
                g = expf(-0.5f * (float)(dx * dx + dy * dy));
            }
            float df = hv - g;
            s1 += df * df;
        }
    }

    // ---------- block reduction (4 waves of 64) ----------
    #pragma unroll
    for (int off = 32; off > 0; off >>= 1) {
        s3 += __shfl_down(s3, off);
        s1 += __shfl_down(s1, off);
        float ov = __shfl_down(bv3, off); int oi = __shfl_down(bi3, off);
        if (ov > bv3 || (ov == bv3 && oi < bi3)) { bv3 = ov; bi3 = oi; }
        float ow = __shfl_down(bv2, off); int oj = __shfl_down(bi2, off);
        if (ow > bv2 || (ow == bv2 && oj < bi2)) { bv2 = ow; bi2 = oj; }
    }
    const int wave = tid >> 6;
    if ((tid & 63) == 0) {
        rs1[wave] = s1; rs3[wave] = s3;
        rv2[wave] = bv2; ri2[wave] = bi2;
        rv3[wave] = bv3; ri3[wave] = bi3;
    }
    __syncthreads();

    if (tid == 0) {
        #pragma unroll
        for (int w = 1; w < 4; ++w) {
            s1 += rs1[w]; s3 += rs3[w];
            if (rv3[w] > bv3 || (rv3[w] == bv3 && ri3[w] < bi3)) { bv3 = rv3[w]; bi3 = ri3[w]; }
            if (rv2[w] > bv2 || (rv2[w] == bv2 && ri2[w] < bi2)) { bv2 = rv2[w]; bi2 = ri2[w]; }
        }

        const int b = pair / NJ;
        const int j = pair - b * NJ;
        const float scale = 1.0f / (float)COL;

        // 2D decode + offset gather
        const int am = bi2;
        const int x2 = am % COL, y2 = am / COL;
        float gx = o[((size_t)b * (2 * NJ) + j) * CC + am];
        float gy = o[((size_t)b * (2 * NJ) + NJ + j) * CC + am];
        float x2dx = gx + (float)x2 * scale;
        float x2dy = gy + (float)y2 * scale;

        // 3D decode + offset gather
        const int am3 = bi3;
        const int z3 = am3 / CC; const int r3 = am3 - z3 * CC;
        const int y3 = r3 / COL; const int x3 = r3 - y3 * COL;
        size_t base3 = (size_t)b * (3 * NJ * CC3) + (size_t)j * CC3 + am3;
        float g0 = o3D[base3];
        float g1 = o3D[base3 + (size_t)NJ * CC3];
        float g2 = o3D[base3 + (size_t)(2 * NJ) * CC3];
        float x3dx = g0 + (float)x3 * scale;
        float x3dy = g1 + (float)y3 * scale;
        float x3dz = g2 + (float)(z3 - 7) * scale;
        if (vis && !valid2d) { x3dx = 0.f; x3dy = 0.f; x3dz = 0.f; }

        float d2x = (x2dx - tx) * vf0;
        float d2y = (x2dy - ty) * vf1;
        float s2 = d2x * d2x + d2y * d2y;

        float d4x = (x3dx - t3x) * vf0;
        float d4y = (x3dy - t3y) * vf1;
        float d4z = (x3dz - t3z) * vf2;
        float s4 = d4x * d4x + d4y * d4y + d4z * d4z;

        if (jm) {
            atomicAdd(&acc[0], (double)s1);
            atomicAdd(&acc[2], (double)s3);
            atomicAdd(&acc[4], 1.0);
        }
        if (s2 != 0.f) atomicAdd(&acc[1], (double)s2);
        if (s4 != 0.f) atomicAdd(&acc[3], (double)s4);
        float nvs = vf0 + vf1 + vf2;
        if (nvs != 0.f) atomicAdd(&acc[5], (double)nvs);
    }
}

__global__ void msed_finalize_kernel(const double* __restrict__ acc,
                                     float* __restrict__ out)
{
    double cnt = acc[4];
    double Nv  = acc[5] / 3.0;
    float d1 = (float)(sqrt(acc[0]) / cnt);
    float d2 = (float)(sqrt(acc[1]) / Nv);
    float d3 = (float)(sqrt(acc[2]) / cnt);
    float d4 = (float)(sqrt(acc[3]) / Nv);
    out[0] = d1 + d2 + d3 + d4;
}

extern "C" void kernel_launch(void* const* d_in, const int* in_sizes, int n_in,
                              void* d_out, int out_size, void* d_ws, size_t ws_size,
                              hipStream_t stream)
{
    const float* o   = (const float*)d_in[0];
    const float* h   = (const float*)d_in[1];
    const float* o3D = (const float*)d_in[2];
    const float* h3D = (const float*)d_in[3];
    const float* t   = (const float*)d_in[4];
    const float* t3D = (const float*)d_in[5];
    const float* v   = (const float*)d_in[6];

    const int B = in_sizes[1] / (NJ * CC);
    double* acc = (double*)d_ws;

    hipMemsetAsync(acc, 0, 6 * sizeof(double), stream);
    msed_pair_kernel<<<B * NJ, 256, 0, stream>>>(o, h, o3D, h3D, t, t3D, v, acc);
    msed_finalize_kernel<<<1, 1, 0, stream>>>(acc, (float*)d_out);
}

// Round 2
// 34.093 us; speedup vs baseline: 7.4970x; 7.4970x over previous
//
#include <hip/hip_runtime.h>
#include <float.h>
#include <math.h>

#define NJ   24
#define COL  14
#define CC   196        // COL*COL
#define CC3  2744       // COL^3
#define NV4_3D 686      // CC3/4
#define NV4_2D 49       // CC/4
#define TMPW 3

// Per-pair partials in d_ws: 8 floats per pair: {s1, s2, s3, s4, jm, nvs, 0, 0}
__global__ __launch_bounds__(64)
void msed_pair_kernel(const float* __restrict__ o,
                      const float* __restrict__ h,
                      const float* __restrict__ o3D,
                      const float* __restrict__ h3D,
                      const float* __restrict__ t,
                      const float* __restrict__ t3D,
                      const float* __restrict__ v,
                      float* __restrict__ part)
{
    const int pair = blockIdx.x;     // b*NJ + j
    const int lane = threadIdx.x;    // 0..63, single wave

    // ---- scalar prologue, computed redundantly on all lanes (broadcast loads) ----
    const float tx  = t[pair * 2 + 0];
    const float ty  = t[pair * 2 + 1];
    const float t3x = t3D[pair * 3 + 0];
    const float t3y = t3D[pair * 3 + 1];
    const float t3z = t3D[pair * 3 + 2];
    const float v0  = v[pair * 3 + 0];
    const float v1  = v[pair * 3 + 1];
    const float v2c = v[pair * 3 + 2];
    const bool vis = (v0 == 1.0f);

    const int mux = (int)floorf(tx * (float)COL + 0.5f);
    const int muy = (int)floorf(ty * (float)COL + 0.5f);
    const bool valid2d = !((mux - TMPW >= COL) || (muy - TMPW >= COL) ||
                           (mux + TMPW + 1 <= 0) || (muy + TMPW + 1 <= 0));

    const int m3x = (int)floorf(t3x * (float)COL + 0.5f);
    const int m3y = (int)floorf(t3y * (float)COL + 0.5f);
    const int m3z = (int)floorf(t3z * (float)COL + 7.0f + 0.5f);
    const bool valid3d = !((m3x - TMPW >= COL) || (m3y - TMPW >= COL) || (m3z - TMPW >= COL) ||
                           (m3x + TMPW + 1 < 0) || (m3y + TMPW + 1 < 0) || (m3z + TMPW + 1 < 0));

    const float keep = vis ? ((valid2d && valid3d) ? 1.0f : 0.0f) : 1.0f;
    const float vf0 = v0 * keep, vf1 = v1 * keep, vf2 = v2c * keep;
    const bool jm     = (vf0 != 0.0f);
    const bool active = jm || (vf1 != 0.0f) || (vf2 != 0.0f);
    const bool gate2  = vis && valid2d;
    const bool gate3  = vis && valid2d && valid3d;

    if (!active) {
        if (lane == 0) {
            float4 z4 = make_float4(0.f, 0.f, 0.f, 0.f);
            *(float4*)(part + (size_t)pair * 8)     = z4;
            *(float4*)(part + (size_t)pair * 8 + 4) = z4;
        }
        return;
    }

    // ---------- fused 3D pass: argmax + sum (h3 - tt3)^2 ----------
    const float4* hp3 = (const float4*)(h3D + (size_t)pair * CC3);
    float s3 = 0.0f;
    float bv3 = -FLT_MAX; int bi3 = 0x7FFFFFFF;
    for (int i = lane; i < NV4_3D; i += 64) {
        float4 q = hp3[i];
        float vals[4] = {q.x, q.y, q.z, q.w};
        int e0 = i * 4;
        #pragma unroll
        for (int c = 0; c < 4; ++c) {
            int e = e0 + c;
            float hv = vals[c];
            if (hv > bv3) { bv3 = hv; bi3 = e; }   // per-lane e increasing -> first max kept
            int z = e / CC; int r = e - z * CC; int y = r / COL; int x = r - y * COL;
            float g = 0.0f;
            int dx = x - m3x, dy = y - m3y, dz = z - m3z;
            if (gate3 && abs(dx) <= TMPW && abs(dy) <= TMPW && abs(dz) <= TMPW) {
                g = expf(-0.5f * (float)(dx * dx + dy * dy + dz * dz));
            }
            float df = hv - g;
            s3 += df * df;
        }
    }

    // ---------- fused 2D pass ----------
    float s1 = 0.0f;
    float bv2 = -FLT_MAX; int bi2 = 0x7FFFFFFF;
    if (lane < NV4_2D) {
        const float4* hp2 = (const float4*)(h + (size_t)pair * CC);
        float4 q = hp2[lane];
        float vals[4] = {q.x, q.y, q.z, q.w};
        int e0 = lane * 4;
        #pragma unroll
        for (int c = 0; c < 4; ++c) {
            int e = e0 + c;
            float hv = vals[c];
            if (hv > bv2) { bv2 = hv; bi2 = e; }
            int y = e / COL; int x = e - y * COL;
            float g = 0.0f;
            int dx = x - mux, dy = y - muy;
            if (gate2 && abs(dx) <= TMPW && abs(dy) <= TMPW) {
                g = expf(-0.5f * (float)(dx * dx + dy * dy));
            }
            float df = hv - g;
            s1 += df * df;
        }
    }

    // ---------- single-wave shuffle reduction ----------
    #pragma unroll
    for (int off = 32; off > 0; off >>= 1) {
        s3 += __shfl_down(s3, off);
        s1 += __shfl_down(s1, off);
        float ov = __shfl_down(bv3, off); int oi = __shfl_down(bi3, off);
        if (ov > bv3 || (ov == bv3 && oi < bi3)) { bv3 = ov; bi3 = oi; }
        float ow = __shfl_down(bv2, off); int oj = __shfl_down(bi2, off);
        if (ow > bv2 || (ow == bv2 && oj < bi2)) { bv2 = ow; bi2 = oj; }
    }

    if (lane == 0) {
        const int b = pair / NJ;
        const int j = pair - b * NJ;
        const float scale = 1.0f / (float)COL;

        // 2D decode + offset gather (2 scattered scalar loads)
        const int am = bi2;
        const int x2 = am % COL, y2 = am / COL;
        float gx = o[((size_t)b * (2 * NJ) + j) * CC + am];
        float gy = o[((size_t)b * (2 * NJ) + NJ + j) * CC + am];
        float x2dx = gx + (float)x2 * scale;
        float x2dy = gy + (float)y2 * scale;

        // 3D decode + offset gather (3 scattered scalar loads)
        const int am3 = bi3;
        const int z3 = am3 / CC; const int r3 = am3 - z3 * CC;
        const int y3 = r3 / COL; const int x3 = r3 - y3 * COL;
        size_t base3 = (size_t)b * (3 * NJ * CC3) + (size_t)j * CC3 + am3;
        float g0 = o3D[base3];
        float g1 = o3D[base3 + (size_t)NJ * CC3];
        float g2 = o3D[base3 + (size_t)(2 * NJ) * CC3];
        float x3dx = g0 + (float)x3 * scale;
        float x3dy = g1 + (float)y3 * scale;
        float x3dz = g2 + (float)(z3 - 7) * scale;
        if (vis && !valid2d) { x3dx = 0.f; x3dy = 0.f; x3dz = 0.f; }

        float d2x = (x2dx - tx) * vf0;
        float d2y = (x2dy - ty) * vf1;
        float s2 = d2x * d2x + d2y * d2y;

        float d4x = (x3dx - t3x) * vf0;
        float d4y = (x3dy - t3y) * vf1;
        float d4z = (x3dz - t3z) * vf2;
        float s4 = d4x * d4x + d4y * d4y + d4z * d4z;

        float jmf = jm ? 1.0f : 0.0f;
        // s1/s3 only count when jm (they are zero-masked by jmask in the ref)
        float4 p0 = make_float4(jm ? s1 : 0.f, s2, jm ? s3 : 0.f, s4);
        float4 p1 = make_float4(jmf, vf0 + vf1 + vf2, 0.f, 0.f);
        *(float4*)(part + (size_t)pair * 8)     = p0;
        *(float4*)(part + (size_t)pair * 8 + 4) = p1;
    }
}

// Deterministic tree reduction over npairs x 8 partials, then finalize.
__global__ __launch_bounds__(256)
void msed_reduce_kernel(const float* __restrict__ part, int npairs,
                        float* __restrict__ out)
{
    const int tid = threadIdx.x;
    double a0 = 0, a1 = 0, a2 = 0, a3 = 0, a4 = 0, a5 = 0;
    for (int p = tid; p < npairs; p += 256) {
        const float4 q0 = *(const float4*)(part + (size_t)p * 8);
        const float4 q1 = *(const float4*)(part + (size_t)p * 8 + 4);
        a0 += (double)q0.x; a1 += (double)q0.y; a2 += (double)q0.z; a3 += (double)q0.w;
        a4 += (double)q1.x; a5 += (double)q1.y;
    }

    // intra-wave reduce (doubles via shuffle)
    #pragma unroll
    for (int off = 32; off > 0; off >>= 1) {
        a0 += __shfl_down(a0, off);
        a1 += __shfl_down(a1, off);
        a2 += __shfl_down(a2, off);
        a3 += __shfl_down(a3, off);
        a4 += __shfl_down(a4, off);
        a5 += __shfl_down(a5, off);
    }

    __shared__ double ws[4][6];
    const int wave = tid >> 6;
    if ((tid & 63) == 0) {
        ws[wave][0] = a0; ws[wave][1] = a1; ws[wave][2] = a2;
        ws[wave][3] = a3; ws[wave][4] = a4; ws[wave][5] = a5;
    }
    __syncthreads();

    if (tid == 0) {
        #pragma unroll
        for (int w = 1; w < 4; ++w) {
            a0 += ws[w][0]; a1 += ws[w][1]; a2 += ws[w][2];
            a3 += ws[w][3]; a4 += ws[w][4]; a5 += ws[w][5];
        }
        double cnt = a4;
        double Nv  = a5 / 3.0;
        float d1 = (float)(sqrt(a0) / cnt);
        float d2 = (float)(sqrt(a1) / Nv);
        float d3 = (float)(sqrt(a2) / cnt);
        float d4 = (float)(sqrt(a3) / Nv);
        out[0] = d1 + d2 + d3 + d4;
    }
}

extern "C" void kernel_launch(void* const* d_in, const int* in_sizes, int n_in,
                              void* d_out, int out_size, void* d_ws, size_t ws_size,
                              hipStream_t stream)
{
    const float* o   = (const float*)d_in[0];
    const float* h   = (const float*)d_in[1];
    const float* o3D = (const float*)d_in[2];
    const float* h3D = (const float*)d_in[3];
    const float* t   = (const float*)d_in[4];
    const float* t3D = (const float*)d_in[5];
    const float* v   = (const float*)d_in[6];

    const int B = in_sizes[1] / (NJ * CC);
    const int npairs = B * NJ;
    float* part = (float*)d_ws;      // npairs * 8 floats

    msed_pair_kernel<<<npairs, 64, 0, stream>>>(o, h, o3D, h3D, t, t3D, v, part);
    msed_reduce_kernel<<<1, 256, 0, stream>>>(part, npairs, (float*)d_out);
}

// Round 3
// 23.322 us; speedup vs baseline: 10.9596x; 1.4619x over previous
//
#include <hip/hip_runtime.h>
#include <float.h>
#include <math.h>

#define NJ   24
#define COL  14
#define CC   196        // COL*COL
#define CC3  2744       // COL^3
#define NV4_3D 686      // CC3/4
#define NV4_2D 49       // CC/4
#define TMPW 3

// Per-pair partials in d_ws: 8 floats per pair: {s1, s2, s3, s4, jm, nvs, 0, 0}
//
// Identity used: sum_e (h[e] - tt[e])^2 = sum_e h^2 - sum_{window} g*(2h - g),
// where tt = g = exp(-0.5*r^2) only inside the clipped gaussian window and the
// gates (vis & valid2d [& valid3d]) hold. s1/s3 are only consumed when jm=1,
// and jm=1 implies all gates true, so window terms are gated but the streaming
// pass needs NO per-element coordinate decode or gating at all.
__global__ __launch_bounds__(64)
void msed_pair_kernel(const float* __restrict__ o,
                      const float* __restrict__ h,
                      const float* __restrict__ o3D,
                      const float* __restrict__ h3D,
                      const float* __restrict__ t,
                      const float* __restrict__ t3D,
                      const float* __restrict__ v,
                      float* __restrict__ part)
{
    const int pair = blockIdx.x;     // b*NJ + j
    const int lane = threadIdx.x;    // 0..63, single wave

    // ---- scalar prologue (uniform across lanes -> s_load broadcast) ----
    const float tx  = t[pair * 2 + 0];
    const float ty  = t[pair * 2 + 1];
    const float t3x = t3D[pair * 3 + 0];
    const float t3y = t3D[pair * 3 + 1];
    const float t3z = t3D[pair * 3 + 2];
    const float v0  = v[pair * 3 + 0];
    const float v1  = v[pair * 3 + 1];
    const float v2c = v[pair * 3 + 2];
    const bool vis = (v0 == 1.0f);

    const int mux = (int)floorf(tx * (float)COL + 0.5f);
    const int muy = (int)floorf(ty * (float)COL + 0.5f);
    const bool valid2d = !((mux - TMPW >= COL) || (muy - TMPW >= COL) ||
                           (mux + TMPW + 1 <= 0) || (muy + TMPW + 1 <= 0));

    const int m3x = (int)floorf(t3x * (float)COL + 0.5f);
    const int m3y = (int)floorf(t3y * (float)COL + 0.5f);
    const int m3z = (int)floorf(t3z * (float)COL + 7.0f + 0.5f);
    const bool valid3d = !((m3x - TMPW >= COL) || (m3y - TMPW >= COL) || (m3z - TMPW >= COL) ||
                           (m3x + TMPW + 1 < 0) || (m3y + TMPW + 1 < 0) || (m3z + TMPW + 1 < 0));

    const float keep = vis ? ((valid2d && valid3d) ? 1.0f : 0.0f) : 1.0f;
    const float vf0 = v0 * keep, vf1 = v1 * keep, vf2 = v2c * keep;
    const bool jm     = (vf0 != 0.0f);
    const bool active = jm || (vf1 != 0.0f) || (vf2 != 0.0f);
    const bool gate2  = vis && valid2d;
    const bool gate3  = vis && valid2d && valid3d;

    if (!active) {
        if (lane == 0) {
            float4 z4 = make_float4(0.f, 0.f, 0.f, 0.f);
            *(float4*)(part + (size_t)pair * 8)     = z4;
            *(float4*)(part + (size_t)pair * 8 + 4) = z4;
        }
        return;
    }

    // ---------- streaming 3D pass: sum h^2 + argmax (no coord decode) ----------
    const float4* hp3 = (const float4*)(h3D + (size_t)pair * CC3);
    float s3 = 0.0f;
    float bv3 = -FLT_MAX; int bi3 = 0x7FFFFFFF;
    #pragma unroll
    for (int u = 0; u < 11; ++u) {
        const int i = lane + (u << 6);
        const bool valid = (u < 10) || (lane < (NV4_3D - 640));
        const int ic = valid ? i : lane;       // safe dummy index for tail lanes
        float4 q = hp3[ic];
        float vals[4] = {q.x, q.y, q.z, q.w};
        const int e0 = ic * 4;
        #pragma unroll
        for (int c = 0; c < 4; ++c) {
            float hv = vals[c];
            if (valid) {
                s3 += hv * hv;
                if (hv > bv3) { bv3 = hv; bi3 = e0 + c; }  // per-lane e increasing
            }
        }
    }

    // ---------- streaming 2D pass ----------
    float s1 = 0.0f;
    float bv2 = -FLT_MAX; int bi2 = 0x7FFFFFFF;
    if (lane < NV4_2D) {
        const float4* hp2 = (const float4*)(h + (size_t)pair * CC);
        float4 q = hp2[lane];
        float vals[4] = {q.x, q.y, q.z, q.w};
        const int e0 = lane * 4;
        #pragma unroll
        for (int c = 0; c < 4; ++c) {
            float hv = vals[c];
            s1 += hv * hv;
            if (hv > bv2) { bv2 = hv; bi2 = e0 + c; }
        }
    }

    // ---------- gaussian window corrections (gathers hit L1: data just streamed) ----------
    // lane < 49 -> (dx,dy) in [-3,3]^2
    if (lane < 49) {
        const int dx = lane % 7 - TMPW;
        const int dy = lane / 7 - TMPW;
        const float gxy = __expf(-0.5f * (float)(dx * dx + dy * dy));

        if (gate2) {
            const int x = mux + dx, y = muy + dy;
            if ((unsigned)x < COL && (unsigned)y < COL) {
                const float wh = h[(size_t)pair * CC + y * COL + x];
                s1 += gxy * (gxy - 2.0f * wh);     // adds (h-g)^2 - h^2
            }
        }
        if (gate3) {
            const int x = m3x + dx, y = m3y + dy;
            if ((unsigned)x < COL && (unsigned)y < COL) {
                const float* base = h3D + (size_t)pair * CC3 + y * COL + x;
                #pragma unroll
                for (int dz = -TMPW; dz <= TMPW; ++dz) {
                    const int z = m3z + dz;
                    if ((unsigned)z < COL) {
                        const float g = gxy * __expf(-0.5f * (float)(dz * dz));
                        const float wh = base[z * CC];
                        s3 += g * (g - 2.0f * wh);
                    }
                }
            }
        }
    }

    // ---------- single-wave shuffle reduction ----------
    #pragma unroll
    for (int off = 32; off > 0; off >>= 1) {
        s3 += __shfl_down(s3, off);
        s1 += __shfl_down(s1, off);
        float ov = __shfl_down(bv3, off); int oi = __shfl_down(bi3, off);
        if (ov > bv3 || (ov == bv3 && oi < bi3)) { bv3 = ov; bi3 = oi; }
        float ow = __shfl_down(bv2, off); int oj = __shfl_down(bi2, off);
        if (ow > bv2 || (ow == bv2 && oj < bi2)) { bv2 = ow; bi2 = oj; }
    }

    if (lane == 0) {
        const int b = pair / NJ;
        const int j = pair - b * NJ;
        const float scale = 1.0f / (float)COL;

        // 2D decode + offset gather
        const int am = bi2;
        const int x2 = am % COL, y2 = am / COL;
        float gx = o[((size_t)b * (2 * NJ) + j) * CC + am];
        float gy = o[((size_t)b * (2 * NJ) + NJ + j) * CC + am];
        float x2dx = gx + (float)x2 * scale;
        float x2dy = gy + (float)y2 * scale;

        // 3D decode + offset gather
        const int am3 = bi3;
        const int z3 = am3 / CC; const int r3 = am3 - z3 * CC;
        const int y3 = r3 / COL; const int x3 = r3 - y3 * COL;
        size_t base3 = (size_t)b * (3 * NJ * CC3) + (size_t)j * CC3 + am3;
        float g0 = o3D[base3];
        float g1 = o3D[base3 + (size_t)NJ * CC3];
        float g2 = o3D[base3 + (size_t)(2 * NJ) * CC3];
        float x3dx = g0 + (float)x3 * scale;
        float x3dy = g1 + (float)y3 * scale;
        float x3dz = g2 + (float)(z3 - 7) * scale;
        if (vis && !valid2d) { x3dx = 0.f; x3dy = 0.f; x3dz = 0.f; }

        float d2x = (x2dx - tx) * vf0;
        float d2y = (x2dy - ty) * vf1;
        float s2 = d2x * d2x + d2y * d2y;

        float d4x = (x3dx - t3x) * vf0;
        float d4y = (x3dy - t3y) * vf1;
        float d4z = (x3dz - t3z) * vf2;
        float s4 = d4x * d4x + d4y * d4y + d4z * d4z;

        float jmf = jm ? 1.0f : 0.0f;
        float4 p0 = make_float4(jm ? s1 : 0.f, s2, jm ? s3 : 0.f, s4);
        float4 p1 = make_float4(jmf, vf0 + vf1 + vf2, 0.f, 0.f);
        *(float4*)(part + (size_t)pair * 8)     = p0;
        *(float4*)(part + (size_t)pair * 8 + 4) = p1;
    }
}

// Deterministic tree reduction over npairs x 8 partials, then finalize.
// 1024 threads (16 waves) for latency hiding on the cross-XCD partial reads.
__global__ __launch_bounds__(1024)
void msed_reduce_kernel(const float* __restrict__ part, int npairs,
                        float* __restrict__ out)
{
    const int tid = threadIdx.x;
    double a0 = 0, a1 = 0, a2 = 0, a3 = 0, a4 = 0, a5 = 0;
    for (int p = tid; p < npairs; p += 1024) {
        const float4 q0 = *(const float4*)(part + (size_t)p * 8);
        const float4 q1 = *(const float4*)(part + (size_t)p * 8 + 4);
        a0 += (double)q0.x; a1 += (double)q0.y; a2 += (double)q0.z; a3 += (double)q0.w;
        a4 += (double)q1.x; a5 += (double)q1.y;
    }

    #pragma unroll
    for (int off = 32; off > 0; off >>= 1) {
        a0 += __shfl_down(a0, off);
        a1 += __shfl_down(a1, off);
        a2 += __shfl_down(a2, off);
        a3 += __shfl_down(a3, off);
        a4 += __shfl_down(a4, off);
        a5 += __shfl_down(a5, off);
    }

    __shared__ double ws[16][6];
    const int wave = tid >> 6;
    if ((tid & 63) == 0) {
        ws[wave][0] = a0; ws[wave][1] = a1; ws[wave][2] = a2;
        ws[wave][3] = a3; ws[wave][4] = a4; ws[wave][5] = a5;
    }
    __syncthreads();

    if (tid == 0) {
        #pragma unroll
        for (int w = 1; w < 16; ++w) {
            a0 += ws[w][0]; a1 += ws[w][1]; a2 += ws[w][2];
            a3 += ws[w][3]; a4 += ws[w][4]; a5 += ws[w][5];
        }
        double cnt = a4;
        double Nv  = a5 / 3.0;
        float d1 = (float)(sqrt(a0) / cnt);
        float d2 = (float)(sqrt(a1) / Nv);
        float d3 = (float)(sqrt(a2) / cnt);
        float d4 = (float)(sqrt(a3) / Nv);
        out[0] = d1 + d2 + d3 + d4;
    }
}

extern "C" void kernel_launch(void* const* d_in, const int* in_sizes, int n_in,
                              void* d_out, int out_size, void* d_ws, size_t ws_size,
                              hipStream_t stream)
{
    const float* o   = (const float*)d_in[0];
    const float* h   = (const float*)d_in[1];
    const float* o3D = (const float*)d_in[2];
    const float* h3D = (const float*)d_in[3];
    const float* t   = (const float*)d_in[4];
    const float* t3D = (const float*)d_in[5];
    const float* v   = (const float*)d_in[6];

    const int B = in_sizes[1] / (NJ * CC);
    const int npairs = B * NJ;
    float* part = (float*)d_ws;      // npairs * 8 floats

    msed_pair_kernel<<<npairs, 64, 0, stream>>>(o, h, o3D, h3D, t, t3D, v, part);
    msed_reduce_kernel<<<1, 1024, 0, stream>>>(part, npairs, (float*)d_out);
}